// Round 1
// baseline (145.310 us; speedup 1.0000x reference)
//
#include <hip/hip_runtime.h>
#include <hip/hip_bf16.h>

#define B_DIM 4096
#define D_DIM 768
#define BM 128
#define BN 128
#define BK 64

typedef __bf16 bf16_t;
typedef bf16_t bf16x8 __attribute__((ext_vector_type(8)));
typedef float f32x4 __attribute__((ext_vector_type(4)));

// ---------------- Kernel 1: fp32 -> bf16 + row sum-of-squares ----------------
__global__ __launch_bounds__(256) void prep_kernel(
    const float* __restrict__ E, ushort* __restrict__ Ebf, float* __restrict__ sq)
{
    const int row = blockIdx.x;
    const int tid = threadIdx.x;
    const float* er = E + (size_t)row * D_DIM;
    ushort* br = Ebf + (size_t)row * D_DIM;
    float s = 0.f;
    #pragma unroll
    for (int c = tid; c < D_DIM; c += 256) {
        float v = er[c];
        s += v * v;
        __hip_bfloat16 h = __float2bfloat16(v);
        br[c] = *reinterpret_cast<const ushort*>(&h);
    }
    #pragma unroll
    for (int off = 32; off > 0; off >>= 1) s += __shfl_down(s, off);
    __shared__ float red[4];
    if ((tid & 63) == 0) red[tid >> 6] = s;
    __syncthreads();
    if (tid == 0) sq[row] = red[0] + red[1] + red[2] + red[3];
}

// ---------------- Kernel 2: fused gram GEMM + loss epilogue ----------------
// 128x128 tile, BK=64, 4 waves in 2x2, each wave owns a 64x64 sub-tile
// (4x4 fragments of 16x16x32 bf16 MFMA).
// LDS: linear dest for global_load_lds; source pre-swizzled with
// col ^= (row&7)<<3 (16-byte-chunk XOR) and the same XOR applied on ds_read,
// so the swizzle cancels exactly (rule #21) while spreading the stride-128B
// rows across all 32 banks.
__global__ __launch_bounds__(256) void gram_loss_kernel(
    const ushort* __restrict__ Ebf, const float* __restrict__ sq,
    const float* __restrict__ art, float* __restrict__ out)
{
    __shared__ ushort Als[BM][BK];   // 16 KiB
    __shared__ ushort Bls[BN][BK];   // 16 KiB
    __shared__ float red[4];

    const int tid  = threadIdx.x;
    const int lane = tid & 63;
    const int wave = tid >> 6;
    const int wr = wave >> 1;        // wave row in 2x2
    const int wc = wave & 1;         // wave col in 2x2
    const int tileR = blockIdx.x >> 5;
    const int tileC = blockIdx.x & 31;
    const int row0 = tileR * BM;
    const int col0 = tileC * BN;

    f32x4 acc[4][4] = {};

    const int srow  = tid >> 3;        // 0..31: row within a 32-row staging issue
    const int scol8 = (tid & 7) * 8;   // element col base (linear LDS dest)

    for (int kk = 0; kk < D_DIM; kk += BK) {
        #pragma unroll
        for (int i = 0; i < 4; ++i) {
            const int r = i * 32 + srow;
            const int colg = scol8 ^ ((r & 7) << 3);   // inverse-swizzled source col
            const ushort* gA = Ebf + (size_t)(row0 + r) * D_DIM + kk + colg;
            __builtin_amdgcn_global_load_lds(
                (const __attribute__((address_space(1))) void*)gA,
                (__attribute__((address_space(3))) void*)(&Als[r][scol8]),
                16, 0, 0);
            const ushort* gB = Ebf + (size_t)(col0 + r) * D_DIM + kk + colg;
            __builtin_amdgcn_global_load_lds(
                (const __attribute__((address_space(1))) void*)gB,
                (__attribute__((address_space(3))) void*)(&Bls[r][scol8]),
                16, 0, 0);
        }
        __syncthreads();

        #pragma unroll
        for (int k2 = 0; k2 < BK; k2 += 32) {
            bf16x8 af[4], bfr[4];
            #pragma unroll
            for (int m = 0; m < 4; ++m) {
                const int r = wr * 64 + m * 16 + (lane & 15);
                const int c = (k2 + (lane >> 4) * 8) ^ ((r & 7) << 3);
                af[m] = *reinterpret_cast<const bf16x8*>(&Als[r][c]);
            }
            #pragma unroll
            for (int n = 0; n < 4; ++n) {
                const int r = wc * 64 + n * 16 + (lane & 15);
                const int c = (k2 + (lane >> 4) * 8) ^ ((r & 7) << 3);
                bfr[n] = *reinterpret_cast<const bf16x8*>(&Bls[r][c]);
            }
            #pragma unroll
            for (int m = 0; m < 4; ++m)
                #pragma unroll
                for (int n = 0; n < 4; ++n)
                    acc[m][n] = __builtin_amdgcn_mfma_f32_16x16x32_bf16(
                        af[m], bfr[n], acc[m][n], 0, 0, 0);
        }
        __syncthreads();
    }

    // Epilogue: d2 = sq_i + sq_j - 2*gram; loss term (d2 - art)^2 off-diagonal.
    // C/D layout (HW-verified): col = lane&15, row = (lane>>4)*4 + j.
    float lsum = 0.f;
    const int lr = (lane >> 4) * 4;
    const int lc = lane & 15;
    const int rbase = row0 + wr * 64;
    const int cbase = col0 + wc * 64;
    #pragma unroll
    for (int m = 0; m < 4; ++m) {
        const int gi0 = rbase + m * 16 + lr;
        #pragma unroll
        for (int n = 0; n < 4; ++n) {
            const int gj = cbase + n * 16 + lc;
            const float sqj = sq[gj];
            #pragma unroll
            for (int j = 0; j < 4; ++j) {
                const int gi = gi0 + j;
                const float d2 = sq[gi] + sqj - 2.0f * acc[m][n][j];
                const float t = d2 - art[(size_t)gi * B_DIM + gj];
                if (gi != gj) lsum += t * t;
            }
        }
    }
    #pragma unroll
    for (int off = 32; off > 0; off >>= 1) lsum += __shfl_down(lsum, off);
    if (lane == 0) red[wave] = lsum;
    __syncthreads();
    if (tid == 0) {
        const float inv_pairs = 1.0f / ((float)B_DIM * (float)(B_DIM - 1));
        atomicAdd(out, (red[0] + red[1] + red[2] + red[3]) * inv_pairs);
    }
}

// ---------------- launch ----------------
extern "C" void kernel_launch(void* const* d_in, const int* in_sizes, int n_in,
                              void* d_out, int out_size, void* d_ws, size_t ws_size,
                              hipStream_t stream) {
    const float* E   = (const float*)d_in[0];   // [4096, 768] fp32
    const float* art = (const float*)d_in[1];   // [4096, 4096] fp32
    float* out = (float*)d_out;                 // scalar fp32

    ushort* Ebf = (ushort*)d_ws;                                  // 6,291,456 B
    float*  sq  = (float*)((char*)d_ws + (size_t)B_DIM * D_DIM * 2); // 16 KiB

    hipMemsetAsync(d_out, 0, sizeof(float), stream);
    prep_kernel<<<B_DIM, 256, 0, stream>>>(E, Ebf, sq);
    gram_loss_kernel<<<(B_DIM / BM) * (B_DIM / BN), 256, 0, stream>>>(Ebf, sq, art, out);
}